// Round 6
// baseline (664.185 us; speedup 1.0000x reference)
//
#include <hip/hip_runtime.h>

// CalculateSLayer: a = adj.sum(axis=2) (4096x4096), s_in = a^T @ s, s_out = a @ s.
// Round 6: r5 + FIX of the sTj staging bug that caused r4/r5 NaN in s_out
// (r4 rewrite covered only columns 0..63 of each 128-col sTj row: ii<DP*8,
// d=ii>>3,c=ii&7 -> cols 64..127 stayed uninitialized LDS; case-1 reads them
// at jc>=2 -> NaN-pattern bf16 -> NaN partials. s_in never touches sTj, which
// is why it passed both rounds). Correct loop: DP*16 tasks, d=ii>>4, c=ii&15.
// Re-added the last-block-ticket fused reduction: its machinery was validated
// end-to-end by r4's PASSING output 0 (s_in flowed through it).
// Keeps: single-barrier a-tile dbuf, case-2 register B-frags (validated r5).
// d_out = [s_in (4096x70) | s_out (4096x70)] fp32.

#define N    4096
#define D    70
#define DP   80          // d padded to 5 n-tiles of 16 (rows 70..79 of sT are zero)
#define TILE 128         // block tile (i) x (j)
#define NT_D 5
#define NPART 32         // N/TILE partials per output element
#define ATP  132         // aTt pitch: 264B rows, 8B-aligned (b64 reads), 4-way write conflicts
#define SJP  136         // sTj pitch: 272B rows, 16B-aligned (b128 reads)

typedef short short8  __attribute__((ext_vector_type(8)));   // 8 x bf16 bits
typedef short short4v __attribute__((ext_vector_type(4)));
typedef float f32x4   __attribute__((ext_vector_type(4)));

__device__ __forceinline__ unsigned short f2bf(float f) {
    unsigned u = __builtin_bit_cast(unsigned, f);
    u += 0x7FFFu + ((u >> 16) & 1u);
    return (unsigned short)(u >> 16);
}
__device__ __forceinline__ float bf2f(unsigned short h) {
    unsigned u = (unsigned)h << 16;
    return __builtin_bit_cast(float, u);
}
__device__ __forceinline__ short8 ld_b64x2(const unsigned short* p) {
    short4v lo = *(const short4v*)p;        // 8B aligned
    short4v hi = *(const short4v*)(p + 4);
    return __builtin_shufflevector(lo, hi, 0, 1, 2, 3, 4, 5, 6, 7);
}

// ---------------------------------------------------------------------------
// kernel0: sT[d][n] = bf16(s[n][d]) for d<70, zeros for 70<=d<80 (in d_ws).
// ---------------------------------------------------------------------------
__global__ __launch_bounds__(256) void build_sT(const float* __restrict__ s,
                                                unsigned short* __restrict__ sT) {
    __shared__ unsigned short tile[DP][264];
    const int t  = threadIdx.x;
    const int n0 = blockIdx.x * 256;
    #pragma unroll
    for (int d = 0; d < D; ++d)
        tile[d][t] = f2bf(s[(size_t)(n0 + t) * D + d]);
    __syncthreads();
    #pragma unroll
    for (int d = 0; d < DP; ++d) {
        unsigned short v = (d < D) ? tile[d][t] : (unsigned short)0;
        sT[(size_t)d * N + n0 + t] = v;
    }
}

// ---------------------------------------------------------------------------
// kernel1: per 128x128 tile of a, s_out partial (case 1, contract j) and
// s_in finals-over-block-i (case 2, contract i), mfma_f32_16x16x32_bf16.
// USE_WS=true : bf16 partial stores + last-block-ticket fused reduction.
// USE_WS=false: legacy f32 atomics straight into out (tiny-ws fallback).
// Layouts (verified, learn_hip m89/m120):
//   A-frag: A[m=lane&15][k=quad*8+j]   B-frag: B[k=quad*8+j][n=lane&15]
//   C/D   : col=lane&15, row=quad*4+reg
// ---------------------------------------------------------------------------
template<bool USE_WS>
__global__ __launch_bounds__(512, 4) void fused_slayer(
    const float* __restrict__ adj,
    const unsigned short* __restrict__ sT,
    unsigned short* __restrict__ wsi,   // [32][N][80] bf16 s_in partials
    unsigned short* __restrict__ wso,   // [32][N][80] bf16 s_out partials
    unsigned int*   __restrict__ cnt,   // [64] group tickets (zeroed per call)
    float* __restrict__ out)            // [2][N][70]: s_in | s_out
{
    __shared__ __align__(16) unsigned short a_row[2][TILE][40]; // [buf][i][j_local<32]
    __shared__ __align__(16) unsigned short aTt[2][32][ATP];    // [buf][j_local][i<128]
    __shared__ __align__(16) unsigned short sTj[DP][SJP];       // s rows for j-range
    __shared__ int flag_in, flag_out;

    const int t    = threadIdx.x;
    const int lane = t & 63;
    const int w    = t >> 6;       // wave 0..7
    const int l16  = lane & 15;
    const int q    = lane >> 4;    // quad 0..3
    const int bx   = blockIdx.x;
    const int by   = blockIdx.y;
    const int I0   = by * TILE;
    const int J0   = bx * TILE;

    // ---- stage sTj once: 80 rows x 128 cols bf16 = DP*16 chunk-tasks of 8
    // cols each (FIXED: r4/r5 used DP*8 / c=ii&7, leaving cols 64..127
    // uninitialized -> NaN). First read is after the jc=0 barrier.
    #pragma unroll
    for (int p = 0; p < 3; ++p) {
        int ii = t + 512 * p;
        if (ii < DP * 16) {
            int d = ii >> 4, c = ii & 15;
            *(uint4*)&sTj[d][8 * c] = *(const uint4*)(sT + (size_t)d * N + J0 + 8 * c);
        }
    }

    // ---- case-2 slot assignment + register B-frags direct from global sT ----
    // 10 slots = 2 m-tiles x 5 n-tiles over 8 waves; waves 0,1 take (mt=w, nt=4).
    const int slot_mt = w & 1;
    const int slot_nt = w >> 1;
    const bool extra  = (w < 2);
    short8 bfi[4], bfe[4];
    {
        const int d = 16 * slot_nt + l16;           // < 64
        #pragma unroll
        for (int ks = 0; ks < 4; ++ks)
            bfi[ks] = *(const short8*)(sT + (size_t)d * N + I0 + 32 * ks + 8 * q);
        if (extra) {
            const int d2 = 64 + l16;                // rows 70..79 are zeros
            #pragma unroll
            for (int ks = 0; ks < 4; ++ks)
                bfe[ks] = *(const short8*)(sT + (size_t)d2 * N + I0 + 32 * ks + 8 * q);
        }
    }

    const f32x4 zero = {0.0f, 0.0f, 0.0f, 0.0f};
    f32x4 acc1[NT_D];
    #pragma unroll
    for (int nt = 0; nt < NT_D; ++nt) acc1[nt] = zero;

    const int jp = t & 15;   // j-pair within 32-wide chunk
    const int ir = t >> 4;   // 0..31

    // ---- preload chunk 0 ----
    float4 v[4];
    #pragma unroll
    for (int it = 0; it < 4; ++it) {
        int i = 32 * it + ir;
        v[it] = *(const float4*)(adj + (size_t)(I0 + i) * (2 * N)
                                     + (size_t)(J0 + 2 * jp) * 2);
    }

    #pragma unroll
    for (int jc = 0; jc < 4; ++jc) {
        const int b = jc & 1;

        // (A) convert chunk jc into buffer b.
        // dbuf proof: buffer b's previous readers (iter jc-2) drained their
        // ds_reads at barrier(jc-1) (compiler emits lgkmcnt(0) before
        // s_barrier); these writes are after that barrier.
        #pragma unroll
        for (int it = 0; it < 4; ++it) {
            int i = 32 * it + ir;
            unsigned short b0 = f2bf(v[it].x + v[it].y);   // a = ch0 + ch1
            unsigned short b1 = f2bf(v[it].z + v[it].w);
            *(unsigned int*)&a_row[b][i][2 * jp] =
                (unsigned int)b0 | ((unsigned int)b1 << 16);
            aTt[b][2 * jp][i]     = b0;   // 4-way-conflict b16 transpose stores
            aTt[b][2 * jp + 1][i] = b1;
        }
        __syncthreads();   // the only barrier per chunk

        // (C) prefetch chunk jc+1 (in flight across MFMA + stores + next (A))
        if (jc < 3) {
            #pragma unroll
            for (int it = 0; it < 4; ++it) {
                int i = 32 * it + ir;
                v[it] = *(const float4*)(adj + (size_t)(I0 + i) * (2 * N)
                                             + (size_t)(J0 + 32 * (jc + 1) + 2 * jp) * 2);
            }
        }

        // ---- case 1: s_out += a_tile @ s_j ----
        {
            short8 af = *(const short8*)&a_row[b][16 * w + l16][8 * q];
            #pragma unroll
            for (int nt = 0; nt < NT_D; ++nt) {
                short8 bf = *(const short8*)&sTj[16 * nt + l16][32 * jc + 8 * q];
                acc1[nt] = __builtin_amdgcn_mfma_f32_16x16x32_bf16(af, bf, acc1[nt], 0, 0, 0);
            }
        }

        // ---- case 2: s_in finals for this chunk's 32 j's ----
        {
            f32x4 acc2 = zero;
            #pragma unroll
            for (int ks = 0; ks < 4; ++ks) {
                short8 af2 = ld_b64x2(&aTt[b][16 * slot_mt + l16][32 * ks + 8 * q]);
                acc2 = __builtin_amdgcn_mfma_f32_16x16x32_bf16(af2, bfi[ks], acc2, 0, 0, 0);
            }
            const int d = 16 * slot_nt + l16;
            #pragma unroll
            for (int r = 0; r < 4; ++r) {
                int gj = J0 + 32 * jc + 16 * slot_mt + 4 * q + r;
                if (USE_WS) {
                    wsi[((size_t)by * N + gj) * DP + d] = f2bf(acc2[r]);
                } else if (d < D) {
                    atomicAdd(&out[(size_t)gj * D + d], acc2[r]);
                }
            }
            if (extra) {
                f32x4 acc3 = zero;
                #pragma unroll
                for (int ks = 0; ks < 4; ++ks) {
                    short8 af3 = ld_b64x2(&aTt[b][16 * w + l16][32 * ks + 8 * q]);
                    acc3 = __builtin_amdgcn_mfma_f32_16x16x32_bf16(af3, bfe[ks], acc3, 0, 0, 0);
                }
                const int d2 = 64 + l16;
                #pragma unroll
                for (int r = 0; r < 4; ++r) {
                    int gj = J0 + 32 * jc + 16 * w + 4 * q + r;
                    if (USE_WS) {
                        wsi[((size_t)by * N + gj) * DP + d2] = f2bf(acc3[r]);
                    } else if (d2 < D) {
                        atomicAdd(&out[(size_t)gj * D + d2], acc3[r]);
                    }
                }
            }
        }
    }

    // ---- case-1 epilogue: s_out partial for this block's i-range ----
    #pragma unroll
    for (int nt = 0; nt < NT_D; ++nt) {
        const int d = 16 * nt + l16;
        #pragma unroll
        for (int r = 0; r < 4; ++r) {
            int gi = I0 + 16 * w + 4 * q + r;
            if (USE_WS) {
                wso[((size_t)bx * N + gi) * DP + d] = f2bf(acc1[nt][r]);
            } else if (d < D) {
                atomicAdd(&out[(size_t)N * D + (size_t)gi * D + d], acc1[nt][r]);
            }
        }
    }

    if (!USE_WS) return;

    // ---- last-block ticket + in-kernel reduction ----
    // Machinery validated end-to-end by r4's passing s_in output.
    __threadfence();        // release: my ws stores visible before ticket
    __syncthreads();        // all threads' stores issued before t0 tickets
    if (t == 0) {
        flag_in  = (atomicAdd(&cnt[bx],      1u) == NPART - 1);
        flag_out = (atomicAdd(&cnt[32 + by], 1u) == NPART - 1);
    }
    __syncthreads();

    if (flag_in) {          // reduce s_in group bx: j in [J0, J0+128)
        __threadfence();    // acquire
        for (int task = t; task < TILE * (DP / 8); task += 512) {
            const int jl = task / (DP / 8);
            const int g  = task % (DP / 8);
            const int gj = J0 + jl;
            float acc[8];
            #pragma unroll
            for (int e = 0; e < 8; ++e) acc[e] = 0.0f;
            #pragma unroll 8
            for (int p = 0; p < NPART; ++p) {
                short8 vv = *(const short8*)(wsi + ((size_t)p * N + gj) * DP + 8 * g);
                #pragma unroll
                for (int e = 0; e < 8; ++e) acc[e] += bf2f((unsigned short)vv[e]);
            }
            #pragma unroll
            for (int e = 0; e < 8; ++e) {
                int d = 8 * g + e;
                if (d < D) out[(size_t)gj * D + d] = acc[e];
            }
        }
    }
    if (flag_out) {         // reduce s_out group by: i in [I0, I0+128)
        __threadfence();    // acquire
        for (int task = t; task < TILE * (DP / 8); task += 512) {
            const int il = task / (DP / 8);
            const int g  = task % (DP / 8);
            const int gi = I0 + il;
            float acc[8];
            #pragma unroll
            for (int e = 0; e < 8; ++e) acc[e] = 0.0f;
            #pragma unroll 8
            for (int p = 0; p < NPART; ++p) {
                short8 vv = *(const short8*)(wso + ((size_t)p * N + gi) * DP + 8 * g);
                #pragma unroll
                for (int e = 0; e < 8; ++e) acc[e] += bf2f((unsigned short)vv[e]);
            }
            #pragma unroll
            for (int e = 0; e < 8; ++e) {
                int d = 8 * g + e;
                if (d < D) out[(size_t)N * D + (size_t)gi * D + d] = acc[e];
            }
        }
    }
}

// ---------------------------------------------------------------------------
extern "C" void kernel_launch(void* const* d_in, const int* in_sizes, int n_in,
                              void* d_out, int out_size, void* d_ws, size_t ws_size,
                              hipStream_t stream) {
    const float* adj = (const float*)d_in[0];
    const float* s   = (const float*)d_in[1];
    float* out = (float*)d_out;

    unsigned short* sT = (unsigned short*)d_ws;              // 80*4096*2 = 655,360 B
    const size_t ST_BYTES   = (size_t)DP * N * sizeof(unsigned short);
    unsigned int*   cnt     = (unsigned int*)((char*)d_ws + ST_BYTES);  // 256 B
    unsigned short* ws_part = (unsigned short*)((char*)d_ws + ST_BYTES + 256);
    const size_t PART_ELEMS = (size_t)NPART * N * DP;        // per output
    const size_t NEED = ST_BYTES + 256
                      + 2 * PART_ELEMS * sizeof(unsigned short); // ~42.6 MB

    build_sT<<<dim3(N / 256), dim3(256), 0, stream>>>(s, sT);

    if (ws_size >= NEED) {
        hipMemsetAsync(cnt, 0, 256, stream);   // tickets must start at 0
        fused_slayer<true><<<dim3(N / TILE, N / TILE), dim3(512), 0, stream>>>(
            adj, sT, ws_part, ws_part + PART_ELEMS, cnt, out);
    } else {
        hipMemsetAsync(d_out, 0, (size_t)2 * N * D * sizeof(float), stream);
        fused_slayer<false><<<dim3(N / TILE, N / TILE), dim3(512), 0, stream>>>(
            adj, sT, nullptr, nullptr, nullptr, out);
    }
}

// Round 7
// 210.992 us; speedup vs baseline: 3.1479x; 3.1479x over previous
//
#include <hip/hip_runtime.h>

// CalculateSLayer: a = adj.sum(axis=2) (4096x4096), s_in = a^T @ s, s_out = a @ s.
// Round 7 = the proven-good set, nothing experimental:
//   - two-kernel structure (fused GEMM -> bf16 ws partials -> reduce kernel),
//     r3 PASSED 212us
//   - sTj staging FIX (full 128-col coverage; r4/r5 half-covered -> NaN), r6
//   - single-barrier a-tile double-buffer + case-2 register B-frags + aTt
//     pitch 132 (conflicts 3.9M -> 1.6M), correctness-validated r5/r6
// Round-6 POST-MORTEM: in-kernel last-block-ticket reduction is CORRECT but
// costs ~450us: __threadfence() device-scope release per block (x1024) emits
// vmcnt(0)+L2-writeback, serializing at TCC; acquire fences invalidate L2
// (FETCH 68->89MB). Rule: no device-scope fences in the hot path here.
// d_out = [s_in (4096x70) | s_out (4096x70)] fp32.

#define N    4096
#define D    70
#define DP   80          // d padded to 5 n-tiles of 16 (rows 70..79 of sT are zero)
#define TILE 128         // block tile (i) x (j)
#define NT_D 5
#define NPART 32         // N/TILE partials per output element
#define ATP  132         // aTt pitch: 264B rows, 8B-aligned (b64 reads), 4-way write conflicts
#define SJP  136         // sTj pitch: 272B rows, 16B-aligned (b128 reads)

typedef short short8  __attribute__((ext_vector_type(8)));   // 8 x bf16 bits
typedef short short4v __attribute__((ext_vector_type(4)));
typedef float f32x4   __attribute__((ext_vector_type(4)));

__device__ __forceinline__ unsigned short f2bf(float f) {
    unsigned u = __builtin_bit_cast(unsigned, f);
    u += 0x7FFFu + ((u >> 16) & 1u);
    return (unsigned short)(u >> 16);
}
__device__ __forceinline__ float bf2f(unsigned short h) {
    unsigned u = (unsigned)h << 16;
    return __builtin_bit_cast(float, u);
}
__device__ __forceinline__ short8 ld_b64x2(const unsigned short* p) {
    short4v lo = *(const short4v*)p;        // 8B aligned
    short4v hi = *(const short4v*)(p + 4);
    return __builtin_shufflevector(lo, hi, 0, 1, 2, 3, 4, 5, 6, 7);
}

// ---------------------------------------------------------------------------
// kernel0: sT[d][n] = bf16(s[n][d]) for d<70, zeros for 70<=d<80 (in d_ws).
// ---------------------------------------------------------------------------
__global__ __launch_bounds__(256) void build_sT(const float* __restrict__ s,
                                                unsigned short* __restrict__ sT) {
    __shared__ unsigned short tile[DP][264];
    const int t  = threadIdx.x;
    const int n0 = blockIdx.x * 256;
    #pragma unroll
    for (int d = 0; d < D; ++d)
        tile[d][t] = f2bf(s[(size_t)(n0 + t) * D + d]);
    __syncthreads();
    #pragma unroll
    for (int d = 0; d < DP; ++d) {
        unsigned short v = (d < D) ? tile[d][t] : (unsigned short)0;
        sT[(size_t)d * N + n0 + t] = v;
    }
}

// ---------------------------------------------------------------------------
// kernel1: per 128x128 tile of a, s_out partial (case 1, contract j) and
// s_in finals-over-block-i (case 2, contract i), mfma_f32_16x16x32_bf16.
// USE_WS=true : bf16 partial stores to ws.  false: legacy f32 atomics to out.
// Layouts (verified, learn_hip m89/m120):
//   A-frag: A[m=lane&15][k=quad*8+j]   B-frag: B[k=quad*8+j][n=lane&15]
//   C/D   : col=lane&15, row=quad*4+reg
// ---------------------------------------------------------------------------
template<bool USE_WS>
__global__ __launch_bounds__(512, 4) void fused_slayer(
    const float* __restrict__ adj,
    const unsigned short* __restrict__ sT,
    unsigned short* __restrict__ wsi,   // [32][N][80] bf16 s_in partials
    unsigned short* __restrict__ wso,   // [32][N][80] bf16 s_out partials
    float* __restrict__ out)            // fallback: [2][N][70] f32
{
    __shared__ __align__(16) unsigned short a_row[2][TILE][40]; // [buf][i][j_local<32]
    __shared__ __align__(16) unsigned short aTt[2][32][ATP];    // [buf][j_local][i<128]
    __shared__ __align__(16) unsigned short sTj[DP][SJP];       // s rows for j-range

    const int t    = threadIdx.x;
    const int lane = t & 63;
    const int w    = t >> 6;       // wave 0..7
    const int l16  = lane & 15;
    const int q    = lane >> 4;    // quad 0..3
    const int bx   = blockIdx.x;
    const int by   = blockIdx.y;
    const int I0   = by * TILE;
    const int J0   = bx * TILE;

    // ---- stage sTj once: 80 rows x 128 cols bf16 = DP*16 chunk-tasks of
    // 8 cols each. (r4/r5 bug: DP*8 / c=ii&7 covered only cols 0..63.)
    // First read is after the jc=0 barrier, so no extra barrier needed.
    #pragma unroll
    for (int p = 0; p < 3; ++p) {
        int ii = t + 512 * p;
        if (ii < DP * 16) {
            int d = ii >> 4, c = ii & 15;
            *(uint4*)&sTj[d][8 * c] = *(const uint4*)(sT + (size_t)d * N + J0 + 8 * c);
        }
    }

    // ---- case-2 slot assignment + register B-frags direct from global sT ----
    // 10 slots = 2 m-tiles x 5 n-tiles over 8 waves; waves 0,1 take (mt=w, nt=4).
    const int slot_mt = w & 1;
    const int slot_nt = w >> 1;
    const bool extra  = (w < 2);
    short8 bfi[4], bfe[4];
    {
        const int d = 16 * slot_nt + l16;           // < 64
        #pragma unroll
        for (int ks = 0; ks < 4; ++ks)
            bfi[ks] = *(const short8*)(sT + (size_t)d * N + I0 + 32 * ks + 8 * q);
        if (extra) {
            const int d2 = 64 + l16;                // rows 70..79 are zeros
            #pragma unroll
            for (int ks = 0; ks < 4; ++ks)
                bfe[ks] = *(const short8*)(sT + (size_t)d2 * N + I0 + 32 * ks + 8 * q);
        }
    }

    const f32x4 zero = {0.0f, 0.0f, 0.0f, 0.0f};
    f32x4 acc1[NT_D];
    #pragma unroll
    for (int nt = 0; nt < NT_D; ++nt) acc1[nt] = zero;

    const int jp = t & 15;   // j-pair within 32-wide chunk
    const int ir = t >> 4;   // 0..31

    // ---- preload chunk 0 ----
    float4 v[4];
    #pragma unroll
    for (int it = 0; it < 4; ++it) {
        int i = 32 * it + ir;
        v[it] = *(const float4*)(adj + (size_t)(I0 + i) * (2 * N)
                                     + (size_t)(J0 + 2 * jp) * 2);
    }

    #pragma unroll
    for (int jc = 0; jc < 4; ++jc) {
        const int b = jc & 1;

        // (A) convert chunk jc into buffer b.
        // dbuf proof: buffer b's previous readers (iter jc-2) drained their
        // ds_reads at barrier(jc-1); these writes are after that barrier.
        #pragma unroll
        for (int it = 0; it < 4; ++it) {
            int i = 32 * it + ir;
            unsigned short b0 = f2bf(v[it].x + v[it].y);   // a = ch0 + ch1
            unsigned short b1 = f2bf(v[it].z + v[it].w);
            *(unsigned int*)&a_row[b][i][2 * jp] =
                (unsigned int)b0 | ((unsigned int)b1 << 16);
            aTt[b][2 * jp][i]     = b0;   // 4-way-conflict b16 transpose stores
            aTt[b][2 * jp + 1][i] = b1;
        }
        __syncthreads();   // the only barrier per chunk

        // (C) prefetch chunk jc+1 (in flight across MFMA + stores + next (A))
        if (jc < 3) {
            #pragma unroll
            for (int it = 0; it < 4; ++it) {
                int i = 32 * it + ir;
                v[it] = *(const float4*)(adj + (size_t)(I0 + i) * (2 * N)
                                             + (size_t)(J0 + 32 * (jc + 1) + 2 * jp) * 2);
            }
        }

        // ---- case 1: s_out += a_tile @ s_j ----
        {
            short8 af = *(const short8*)&a_row[b][16 * w + l16][8 * q];
            #pragma unroll
            for (int nt = 0; nt < NT_D; ++nt) {
                short8 bf = *(const short8*)&sTj[16 * nt + l16][32 * jc + 8 * q];
                acc1[nt] = __builtin_amdgcn_mfma_f32_16x16x32_bf16(af, bf, acc1[nt], 0, 0, 0);
            }
        }

        // ---- case 2: s_in finals for this chunk's 32 j's ----
        {
            f32x4 acc2 = zero;
            #pragma unroll
            for (int ks = 0; ks < 4; ++ks) {
                short8 af2 = ld_b64x2(&aTt[b][16 * slot_mt + l16][32 * ks + 8 * q]);
                acc2 = __builtin_amdgcn_mfma_f32_16x16x32_bf16(af2, bfi[ks], acc2, 0, 0, 0);
            }
            const int d = 16 * slot_nt + l16;
            #pragma unroll
            for (int r = 0; r < 4; ++r) {
                int gj = J0 + 32 * jc + 16 * slot_mt + 4 * q + r;
                if (USE_WS) {
                    wsi[((size_t)by * N + gj) * DP + d] = f2bf(acc2[r]);
                } else if (d < D) {
                    atomicAdd(&out[(size_t)gj * D + d], acc2[r]);
                }
            }
            if (extra) {
                f32x4 acc3 = zero;
                #pragma unroll
                for (int ks = 0; ks < 4; ++ks) {
                    short8 af3 = ld_b64x2(&aTt[b][16 * w + l16][32 * ks + 8 * q]);
                    acc3 = __builtin_amdgcn_mfma_f32_16x16x32_bf16(af3, bfe[ks], acc3, 0, 0, 0);
                }
                const int d2 = 64 + l16;
                #pragma unroll
                for (int r = 0; r < 4; ++r) {
                    int gj = J0 + 32 * jc + 16 * w + 4 * q + r;
                    if (USE_WS) {
                        wsi[((size_t)by * N + gj) * DP + d2] = f2bf(acc3[r]);
                    } else if (d2 < D) {
                        atomicAdd(&out[(size_t)gj * D + d2], acc3[r]);
                    }
                }
            }
        }
    }

    // ---- case-1 epilogue: s_out partial for this block's i-range ----
    #pragma unroll
    for (int nt = 0; nt < NT_D; ++nt) {
        const int d = 16 * nt + l16;
        #pragma unroll
        for (int r = 0; r < 4; ++r) {
            int gi = I0 + 16 * w + 4 * q + r;
            if (USE_WS) {
                wso[((size_t)bx * N + gi) * DP + d] = f2bf(acc1[nt][r]);
            } else if (d < D) {
                atomicAdd(&out[(size_t)N * D + (size_t)gi * D + d], acc1[nt][r]);
            }
        }
    }
}

// ---------------------------------------------------------------------------
// kernel2: reduce 32 bf16 partials -> f32 out.
// ws layout: ushort [which][part<32][N][80]. One thread per (which, j, 8-d
// group); 2*4096*10 = 81920 threads; 128-thread blocks -> 640 blocks.
// ---------------------------------------------------------------------------
__global__ __launch_bounds__(128) void reduce_partials(
    const unsigned short* __restrict__ ws, float* __restrict__ out) {
    const int idx   = blockIdx.x * 128 + threadIdx.x;      // 0 .. 81919
    const int which = idx / (N * (DP / 8));
    const int rem   = idx % (N * (DP / 8));
    const int j     = rem / (DP / 8);
    const int g     = rem % (DP / 8);

    const unsigned short* base = ws + (size_t)which * ((size_t)NPART * N * DP)
                                    + (size_t)j * DP + 8 * g;
    float acc[8];
    #pragma unroll
    for (int e = 0; e < 8; ++e) acc[e] = 0.0f;
    #pragma unroll 8
    for (int p = 0; p < NPART; ++p) {
        short8 v = *(const short8*)(base + (size_t)p * N * DP);
        #pragma unroll
        for (int e = 0; e < 8; ++e)
            acc[e] += bf2f((unsigned short)v[e]);
    }

    float* o = out + (size_t)which * (N * D) + (size_t)j * D;
    #pragma unroll
    for (int e = 0; e < 8; ++e) {
        int d = 8 * g + e;
        if (d < D) o[d] = acc[e];
    }
}

// ---------------------------------------------------------------------------
extern "C" void kernel_launch(void* const* d_in, const int* in_sizes, int n_in,
                              void* d_out, int out_size, void* d_ws, size_t ws_size,
                              hipStream_t stream) {
    const float* adj = (const float*)d_in[0];
    const float* s   = (const float*)d_in[1];
    float* out = (float*)d_out;

    unsigned short* sT = (unsigned short*)d_ws;              // 80*4096*2 = 655,360 B
    const size_t ST_BYTES   = (size_t)DP * N * sizeof(unsigned short);
    unsigned short* ws_part = (unsigned short*)((char*)d_ws + ST_BYTES);
    const size_t PART_ELEMS = (size_t)NPART * N * DP;        // per output
    const size_t NEED = ST_BYTES + 2 * PART_ELEMS * sizeof(unsigned short); // ~42.6 MB

    build_sT<<<dim3(N / 256), dim3(256), 0, stream>>>(s, sT);

    if (ws_size >= NEED) {
        fused_slayer<true><<<dim3(N / TILE, N / TILE), dim3(512), 0, stream>>>(
            adj, sT, ws_part, ws_part + PART_ELEMS, out);
        reduce_partials<<<dim3(2 * N * (DP / 8) / 128), dim3(128), 0, stream>>>(
            ws_part, out);
    } else {
        hipMemsetAsync(d_out, 0, (size_t)2 * N * D * sizeof(float), stream);
        fused_slayer<false><<<dim3(N / TILE, N / TILE), dim3(512), 0, stream>>>(
            adj, sT, nullptr, nullptr, out);
    }
}